// Round 1
// baseline (451.629 us; speedup 1.0000x reference)
//
#include <hip/hip_runtime.h>
#include <hip/hip_bf16.h>

#define NN 50000
#define EE 800000
#define ET (EE + NN)   // edges + self-loops
#define NEG_SLOPE 0.2f
#define EPSF 1e-16f

// ---------------------------------------------------------------------------
// K0: h1 = x @ W1  (N x 128 @ 128 x 128), fused a_src1/a_dst1 epilogue.
// Block = 256 threads handles 32 nodes x 128 channels; thread = 4 nodes x 4 ch.
// ---------------------------------------------------------------------------
__global__ __launch_bounds__(256) void gemm1_k(
    const float* __restrict__ x, const float* __restrict__ W1,
    const float* __restrict__ att_src1, const float* __restrict__ att_dst1,
    float* __restrict__ h1, float* __restrict__ as1, float* __restrict__ ad1) {
  __shared__ float Wt[32][128];   // k-tile x channels (16 KB)
  __shared__ float Xt[32][36];    // nodes x k-tile, padded (+4) vs bank conflicts

  const int t  = threadIdx.x;
  const int tx = t & 31;          // channel group: channels tx*4 .. tx*4+3
  const int ty = t >> 5;          // node subgroup 0..7 (4 nodes each)
  const int nodeBase = blockIdx.x * 32;

  float acc[4][4];
  #pragma unroll
  for (int i = 0; i < 4; i++)
    #pragma unroll
    for (int j = 0; j < 4; j++) acc[i][j] = 0.f;

  for (int kb = 0; kb < 128; kb += 32) {
    // stage W tile: 32x128 floats
    #pragma unroll
    for (int i = 0; i < 4; i++) {
      int v = t + i * 256;             // [0,1024) float4 slots
      int row = v >> 5, c4 = v & 31;
      *(float4*)&Wt[row][c4 * 4] =
          *(const float4*)&W1[(kb + row) * 128 + c4 * 4];
    }
    // stage X tile: 32 nodes x 32 k
    {
      int n = t >> 3, c4 = t & 7;
      int gn = nodeBase + n; if (gn >= NN) gn = NN - 1;
      *(float4*)&Xt[n][c4 * 4] =
          *(const float4*)&x[gn * 128 + kb + c4 * 4];
    }
    __syncthreads();
    #pragma unroll
    for (int k = 0; k < 32; k++) {
      float4 w = *(const float4*)&Wt[k][tx * 4];
      #pragma unroll
      for (int i = 0; i < 4; i++) {
        float xv = Xt[ty * 4 + i][k];
        acc[i][0] += xv * w.x;
        acc[i][1] += xv * w.y;
        acc[i][2] += xv * w.z;
        acc[i][3] += xv * w.w;
      }
    }
    __syncthreads();
  }

  // epilogue: store h1, reduce attention dots over the 8 threads of each head
  const float4 as4 = *(const float4*)&att_src1[tx * 4];  // flat [4][32] == [128]
  const float4 ad4 = *(const float4*)&att_dst1[tx * 4];
  const int head = tx >> 3;

  #pragma unroll
  for (int i = 0; i < 4; i++) {
    int gn = nodeBase + ty * 4 + i;
    float ps = acc[i][0] * as4.x + acc[i][1] * as4.y + acc[i][2] * as4.z + acc[i][3] * as4.w;
    float pd = acc[i][0] * ad4.x + acc[i][1] * ad4.y + acc[i][2] * ad4.z + acc[i][3] * ad4.w;
    #pragma unroll
    for (int off = 4; off; off >>= 1) {
      ps += __shfl_down(ps, off, 8);
      pd += __shfl_down(pd, off, 8);
    }
    if (gn < NN) {
      float4 v = make_float4(acc[i][0], acc[i][1], acc[i][2], acc[i][3]);
      *(float4*)&h1[gn * 128 + tx * 4] = v;
      if ((tx & 7) == 0) {
        as1[gn * 4 + head] = ps;
        ad1[gn * 4 + head] = pd;
      }
    }
  }
}

// ---------------------------------------------------------------------------
// CSR build: count -> scan -> scatter  (dst-keyed, includes self-loops)
// edge_index layout: ei[0..E) = src row, ei[E..2E) = dst row.
// ---------------------------------------------------------------------------
__global__ void count_k(const int* __restrict__ ei, int* __restrict__ counts) {
  int i = blockIdx.x * blockDim.x + threadIdx.x;
  if (i >= ET) return;
  int d = (i < EE) ? ei[EE + i] : (i - EE);
  atomicAdd(&counts[d], 1);
}

__global__ __launch_bounds__(1024) void scan_k(const int* __restrict__ counts,
                                               int* __restrict__ offs) {
  __shared__ int part[1024];
  const int t = threadIdx.x;
  const int CH = (NN + 1023) / 1024;  // 49
  int base = t * CH;
  int sum = 0;
  for (int i = 0; i < CH; i++) {
    int idx = base + i;
    if (idx < NN) sum += counts[idx];
  }
  part[t] = sum;
  __syncthreads();
  for (int off = 1; off < 1024; off <<= 1) {
    int v = (t >= off) ? part[t - off] : 0;
    __syncthreads();
    part[t] += v;
    __syncthreads();
  }
  int run = part[t] - sum;  // exclusive
  for (int i = 0; i < CH; i++) {
    int idx = base + i;
    if (idx < NN) { offs[idx] = run; run += counts[idx]; }
  }
  if (t == 1023) offs[NN] = part[1023];
}

__global__ void scatter_k(const int* __restrict__ ei, const int* __restrict__ offs,
                          int* __restrict__ cursor, int* __restrict__ csr) {
  int i = blockIdx.x * blockDim.x + threadIdx.x;
  if (i >= ET) return;
  int s, d;
  if (i < EE) { s = ei[i]; d = ei[EE + i]; }
  else        { s = d = i - EE; }
  int pos = offs[d] + atomicAdd(&cursor[d], 1);
  csr[pos] = s;
}

// ---------------------------------------------------------------------------
// K4: layer-1 softmax-aggregate + bias + ELU + (out1 @ W2) + att2 dots.
// One wave per node; lane handles channels 2*lane, 2*lane+1 (head = lane>>4).
// out1 is never materialized.
// ---------------------------------------------------------------------------
__global__ __launch_bounds__(256) void agg1_k(
    const int* __restrict__ offs, const int* __restrict__ csr,
    const float* __restrict__ h1, const float* __restrict__ as1,
    const float* __restrict__ ad1, const float* __restrict__ b1,
    const float* __restrict__ W2, const float* __restrict__ att_src2,
    const float* __restrict__ att_dst2,
    float* __restrict__ h2, float* __restrict__ as2, float* __restrict__ ad2) {
  const int n = blockIdx.x * 4 + (threadIdx.x >> 6);
  if (n >= NN) return;
  const int lane = threadIdx.x & 63;
  const int hd = lane >> 4;

  const int beg = offs[n], end = offs[n + 1];
  const float adv = ad1[n * 4 + hd];

  float m = -1e30f;
  for (int j = beg; j < end; j++) {
    int s = csr[j];
    float e = as1[s * 4 + hd] + adv;
    e = (e > 0.f) ? e : NEG_SLOPE * e;
    m = fmaxf(m, e);
  }

  float den = 0.f;
  float accx = 0.f, accy = 0.f;
  const float2* __restrict__ h1v = (const float2*)h1;
  for (int j = beg; j < end; j++) {
    int s = csr[j];
    float e = as1[s * 4 + hd] + adv;
    e = (e > 0.f) ? e : NEG_SLOPE * e;
    float ex = __expf(e - m);
    den += ex;
    float2 hv = h1v[s * 64 + lane];
    accx += ex * hv.x;
    accy += ex * hv.y;
  }

  float inv = 1.f / (den + EPSF);
  float2 bb = ((const float2*)b1)[lane];
  float ox = accx * inv + bb.x;
  float oy = accy * inv + bb.y;
  ox = (ox > 0.f) ? ox : (__expf(ox) - 1.f);   // ELU
  oy = (oy > 0.f) ? oy : (__expf(oy) - 1.f);

  // h2 partials: rows 2*lane and 2*lane+1 of W2 [128][2]
  float4 wq = ((const float4*)W2)[lane];  // {W2[2l][0], W2[2l][1], W2[2l+1][0], W2[2l+1][1]}
  float p0 = ox * wq.x + oy * wq.z;
  float p1 = ox * wq.y + oy * wq.w;
  #pragma unroll
  for (int off = 32; off; off >>= 1) {
    p0 += __shfl_xor(p0, off, 64);
    p1 += __shfl_xor(p1, off, 64);
  }
  if (lane == 0) {
    h2[n * 2 + 0] = p0;
    h2[n * 2 + 1] = p1;
    as2[n] = p0 * att_src2[0] + p1 * att_src2[1];
    ad2[n] = p0 * att_dst2[0] + p1 * att_dst2[1];
  }
}

// ---------------------------------------------------------------------------
// K5: layer-2 softmax-aggregate (2 ch) + bias + log_softmax. 1 thread/node.
// ---------------------------------------------------------------------------
__global__ void agg2_k(const int* __restrict__ offs, const int* __restrict__ csr,
                       const float* __restrict__ h2, const float* __restrict__ as2,
                       const float* __restrict__ ad2, const float* __restrict__ b2,
                       float* __restrict__ out) {
  int n = blockIdx.x * blockDim.x + threadIdx.x;
  if (n >= NN) return;
  const float adv = ad2[n];
  const int beg = offs[n], end = offs[n + 1];

  float m = -1e30f;
  for (int j = beg; j < end; j++) {
    float e = as2[csr[j]] + adv;
    e = (e > 0.f) ? e : NEG_SLOPE * e;
    m = fmaxf(m, e);
  }
  float den = 0.f, a0 = 0.f, a1 = 0.f;
  const float2* __restrict__ h2v = (const float2*)h2;
  for (int j = beg; j < end; j++) {
    int s = csr[j];
    float e = as2[s] + adv;
    e = (e > 0.f) ? e : NEG_SLOPE * e;
    float ex = __expf(e - m);
    den += ex;
    float2 hv = h2v[s];
    a0 += ex * hv.x;
    a1 += ex * hv.y;
  }
  float inv = 1.f / (den + EPSF);
  float o0 = a0 * inv + b2[0];
  float o1 = a1 * inv + b2[1];
  float mx = fmaxf(o0, o1);
  float lse = mx + __logf(__expf(o0 - mx) + __expf(o1 - mx));
  out[n * 2 + 0] = o0 - lse;
  out[n * 2 + 1] = o1 - lse;
}

// ---------------------------------------------------------------------------
extern "C" void kernel_launch(void* const* d_in, const int* in_sizes, int n_in,
                              void* d_out, int out_size, void* d_ws, size_t ws_size,
                              hipStream_t stream) {
  const float* x        = (const float*)d_in[0];
  const int*   ei       = (const int*)d_in[1];
  const float* W1       = (const float*)d_in[2];
  const float* att_src1 = (const float*)d_in[3];
  const float* att_dst1 = (const float*)d_in[4];
  const float* b1       = (const float*)d_in[5];
  const float* W2       = (const float*)d_in[6];
  const float* att_src2 = (const float*)d_in[7];
  const float* att_dst2 = (const float*)d_in[8];
  const float* b2       = (const float*)d_in[9];
  float* out = (float*)d_out;

  // workspace layout (all 256B-aligned)
  char* p = (char*)d_ws;
  auto alloc = [&](size_t bytes) {
    char* r = p;
    p += (bytes + 255) & ~size_t(255);
    return r;
  };
  float* h1     = (float*)alloc(sizeof(float) * NN * 128);
  float* as1    = (float*)alloc(sizeof(float) * NN * 4);
  float* ad1    = (float*)alloc(sizeof(float) * NN * 4);
  float* h2     = (float*)alloc(sizeof(float) * NN * 2);
  float* as2    = (float*)alloc(sizeof(float) * NN);
  float* ad2    = (float*)alloc(sizeof(float) * NN);
  int*   counts = (int*)alloc(sizeof(int) * NN);
  int*   offs   = (int*)alloc(sizeof(int) * (NN + 1));
  int*   cursor = (int*)alloc(sizeof(int) * NN);
  int*   csr    = (int*)alloc(sizeof(int) * ET);

  hipMemsetAsync(counts, 0, sizeof(int) * NN, stream);
  hipMemsetAsync(cursor, 0, sizeof(int) * NN, stream);

  gemm1_k<<<(NN + 31) / 32, 256, 0, stream>>>(x, W1, att_src1, att_dst1, h1, as1, ad1);
  count_k<<<(ET + 255) / 256, 256, 0, stream>>>(ei, counts);
  scan_k<<<1, 1024, 0, stream>>>(counts, offs);
  scatter_k<<<(ET + 255) / 256, 256, 0, stream>>>(ei, offs, cursor, csr);
  agg1_k<<<(NN + 3) / 4, 256, 0, stream>>>(offs, csr, h1, as1, ad1, b1, W2,
                                           att_src2, att_dst2, h2, as2, ad2);
  agg2_k<<<(NN + 255) / 256, 256, 0, stream>>>(offs, csr, h2, as2, ad2, b2, out);
}

// Round 2
// 319.314 us; speedup vs baseline: 1.4144x; 1.4144x over previous
//
#include <hip/hip_runtime.h>
#include <hip/hip_bf16.h>

#define NN 50000
#define EE 800000
#define ET (EE + NN)   // edges + self-loops
#define NEG_SLOPE 0.2f
#define EPSF 1e-16f

typedef unsigned int uint32;

__device__ __forceinline__ unsigned short f2bf(float f) {
  unsigned int u = __float_as_uint(f);
  unsigned int r = (u + 0x7fffu + ((u >> 16) & 1u)) >> 16;   // RNE
  return (unsigned short)r;
}
__device__ __forceinline__ float bf_lo(uint32 v) { return __uint_as_float(v << 16); }
__device__ __forceinline__ float bf_hi(uint32 v) { return __uint_as_float(v & 0xffff0000u); }

// ---------------------------------------------------------------------------
// K0: h1 = x @ W1 (50000x128 @ 128x128), fused a_src1/a_dst1 epilogue,
// h1 stored as packed bf16x2 (uint per 2 channels). Tail: fused degree count.
// Block = 256 threads -> 32 nodes x 128 ch; thread = 4 nodes x 4 ch.
// ---------------------------------------------------------------------------
__global__ __launch_bounds__(256) void gemm1_count_k(
    const float* __restrict__ x, const float* __restrict__ W1,
    const float* __restrict__ att_src1, const float* __restrict__ att_dst1,
    const int* __restrict__ ei,
    uint32* __restrict__ h1b, float* __restrict__ as1, float* __restrict__ ad1,
    int* __restrict__ counts) {
  __shared__ float Wt[32][128];   // k-tile x channels (16 KB)
  __shared__ float Xt[32][40];    // nodes x k-tile, +8 pad keeps 16B alignment

  const int t  = threadIdx.x;
  const int tx = t & 31;          // channels tx*4 .. tx*4+3
  const int ty = t >> 5;          // node subgroup 0..7 (4 nodes each)
  const int nodeBase = blockIdx.x * 32;

  float acc[4][4];
  #pragma unroll
  for (int i = 0; i < 4; i++)
    #pragma unroll
    for (int j = 0; j < 4; j++) acc[i][j] = 0.f;

  for (int kb = 0; kb < 128; kb += 32) {
    #pragma unroll
    for (int i = 0; i < 4; i++) {
      int v = t + i * 256;             // [0,1024) float4 slots of 32x128 tile
      int row = v >> 5, c4 = v & 31;
      *(float4*)&Wt[row][c4 * 4] =
          *(const float4*)&W1[(kb + row) * 128 + c4 * 4];
    }
    {
      int n = t >> 3, c4 = t & 7;
      int gn = nodeBase + n; if (gn >= NN) gn = NN - 1;
      *(float4*)&Xt[n][c4 * 4] =
          *(const float4*)&x[gn * 128 + kb + c4 * 4];
    }
    __syncthreads();
    #pragma unroll
    for (int k = 0; k < 32; k += 4) {
      float4 xk[4];
      #pragma unroll
      for (int i = 0; i < 4; i++) xk[i] = *(const float4*)&Xt[ty * 4 + i][k];
      #pragma unroll
      for (int kk = 0; kk < 4; kk++) {
        float4 w = *(const float4*)&Wt[k + kk][tx * 4];
        #pragma unroll
        for (int i = 0; i < 4; i++) {
          float xv = (kk == 0) ? xk[i].x : (kk == 1) ? xk[i].y : (kk == 2) ? xk[i].z : xk[i].w;
          acc[i][0] = fmaf(xv, w.x, acc[i][0]);
          acc[i][1] = fmaf(xv, w.y, acc[i][1]);
          acc[i][2] = fmaf(xv, w.z, acc[i][2]);
          acc[i][3] = fmaf(xv, w.w, acc[i][3]);
        }
      }
    }
    __syncthreads();
  }

  const float4 as4 = *(const float4*)&att_src1[tx * 4];  // [4][32] flat == [128]
  const float4 ad4 = *(const float4*)&att_dst1[tx * 4];
  const int head = tx >> 3;

  #pragma unroll
  for (int i = 0; i < 4; i++) {
    int gn = nodeBase + ty * 4 + i;
    float ps = acc[i][0]*as4.x + acc[i][1]*as4.y + acc[i][2]*as4.z + acc[i][3]*as4.w;
    float pd = acc[i][0]*ad4.x + acc[i][1]*ad4.y + acc[i][2]*ad4.z + acc[i][3]*ad4.w;
    #pragma unroll
    for (int off = 4; off; off >>= 1) {
      ps += __shfl_down(ps, off, 8);
      pd += __shfl_down(pd, off, 8);
    }
    if (gn < NN) {
      uint32 p0 = (uint32)f2bf(acc[i][0]) | ((uint32)f2bf(acc[i][1]) << 16);
      uint32 p1 = (uint32)f2bf(acc[i][2]) | ((uint32)f2bf(acc[i][3]) << 16);
      uint2 pk = make_uint2(p0, p1);
      *(uint2*)&h1b[gn * 64 + tx * 2] = pk;
      if ((tx & 7) == 0) {
        as1[gn * 4 + head] = ps;
        ad1[gn * 4 + head] = pd;
      }
    }
  }

  // fused degree count (counts pre-zeroed by memset on the same stream)
  const int stride = gridDim.x * 256;
  for (int i = blockIdx.x * 256 + t; i < ET; i += stride) {
    int d = (i < EE) ? ei[EE + i] : (i - EE);
    atomicAdd(&counts[d], 1);
  }
}

// ---------------------------------------------------------------------------
// exclusive scan of counts -> offs (single block), also leaves offs[NN]=ET
// ---------------------------------------------------------------------------
__global__ __launch_bounds__(1024) void scan_k(const int* __restrict__ counts,
                                               int* __restrict__ offs) {
  __shared__ int part[1024];
  const int t = threadIdx.x;
  const int CH = (NN + 1023) / 1024;  // 49
  int base = t * CH;
  int sum = 0;
  for (int i = 0; i < CH; i++) {
    int idx = base + i;
    if (idx < NN) sum += counts[idx];
  }
  part[t] = sum;
  __syncthreads();
  for (int off = 1; off < 1024; off <<= 1) {
    int v = (t >= off) ? part[t - off] : 0;
    __syncthreads();
    part[t] += v;
    __syncthreads();
  }
  int run = part[t] - sum;  // exclusive
  for (int i = 0; i < CH; i++) {
    int idx = base + i;
    if (idx < NN) { offs[idx] = run; run += counts[idx]; }
  }
  if (t == 1023) offs[NN] = part[1023];
}

__global__ void scatter_k(const int* __restrict__ ei, const int* __restrict__ offs,
                          int* __restrict__ cursor, int* __restrict__ csr) {
  int i = blockIdx.x * blockDim.x + threadIdx.x;
  if (i >= ET) return;
  int s, d;
  if (i < EE) { s = ei[i]; d = ei[EE + i]; }
  else        { s = d = i - EE; }
  int pos = offs[d] + atomicAdd(&cursor[d], 1);
  csr[pos] = s;
}

// ---------------------------------------------------------------------------
// K4: layer-1 softmax-aggregate (single pass, no max-shift) + bias + ELU +
// (out1 @ W2) + att2 dots. One wave per node; lane = channels 2l, 2l+1.
// ---------------------------------------------------------------------------
__global__ __launch_bounds__(256) void agg1_k(
    const int* __restrict__ offs, const int* __restrict__ csr,
    const uint32* __restrict__ h1b, const float* __restrict__ as1,
    const float* __restrict__ ad1, const float* __restrict__ b1,
    const float* __restrict__ W2, const float* __restrict__ att_src2,
    const float* __restrict__ att_dst2,
    float* __restrict__ h2, float* __restrict__ as2, float* __restrict__ ad2) {
  const int lane = threadIdx.x & 63;
  const int n = __builtin_amdgcn_readfirstlane(blockIdx.x * 4 + (threadIdx.x >> 6));
  const int hd = lane >> 4;

  const int beg = __builtin_amdgcn_readfirstlane(offs[n]);
  const int end = __builtin_amdgcn_readfirstlane(offs[n + 1]);
  const float adv = ad1[n * 4 + hd];

  float den = 0.f, accx = 0.f, accy = 0.f;
  int j = beg;
  for (; j + 3 < end; j += 4) {
    int s0 = csr[j], s1 = csr[j + 1], s2 = csr[j + 2], s3 = csr[j + 3];
    float e0 = as1[s0 * 4 + hd] + adv;
    float e1 = as1[s1 * 4 + hd] + adv;
    float e2 = as1[s2 * 4 + hd] + adv;
    float e3 = as1[s3 * 4 + hd] + adv;
    uint32 v0 = h1b[s0 * 64 + lane];
    uint32 v1 = h1b[s1 * 64 + lane];
    uint32 v2 = h1b[s2 * 64 + lane];
    uint32 v3 = h1b[s3 * 64 + lane];
    e0 = (e0 > 0.f) ? e0 : NEG_SLOPE * e0;
    e1 = (e1 > 0.f) ? e1 : NEG_SLOPE * e1;
    e2 = (e2 > 0.f) ? e2 : NEG_SLOPE * e2;
    e3 = (e3 > 0.f) ? e3 : NEG_SLOPE * e3;
    float x0 = __expf(e0), x1 = __expf(e1), x2 = __expf(e2), x3 = __expf(e3);
    den += (x0 + x1) + (x2 + x3);
    accx = fmaf(x0, bf_lo(v0), accx);
    accy = fmaf(x0, bf_hi(v0), accy);
    accx = fmaf(x1, bf_lo(v1), accx);
    accy = fmaf(x1, bf_hi(v1), accy);
    accx = fmaf(x2, bf_lo(v2), accx);
    accy = fmaf(x2, bf_hi(v2), accy);
    accx = fmaf(x3, bf_lo(v3), accx);
    accy = fmaf(x3, bf_hi(v3), accy);
  }
  for (; j < end; j++) {
    int s = csr[j];
    float e = as1[s * 4 + hd] + adv;
    e = (e > 0.f) ? e : NEG_SLOPE * e;
    float ex = __expf(e);
    uint32 v = h1b[s * 64 + lane];
    den += ex;
    accx = fmaf(ex, bf_lo(v), accx);
    accy = fmaf(ex, bf_hi(v), accy);
  }

  float inv = 1.f / (den + EPSF);
  float2 bb = ((const float2*)b1)[lane];
  float ox = accx * inv + bb.x;
  float oy = accy * inv + bb.y;
  ox = (ox > 0.f) ? ox : (__expf(ox) - 1.f);   // ELU
  oy = (oy > 0.f) ? oy : (__expf(oy) - 1.f);

  float4 wq = ((const float4*)W2)[lane];  // rows 2l, 2l+1 of W2[128][2]
  float p0 = ox * wq.x + oy * wq.z;
  float p1 = ox * wq.y + oy * wq.w;
  #pragma unroll
  for (int off = 32; off; off >>= 1) {
    p0 += __shfl_xor(p0, off, 64);
    p1 += __shfl_xor(p1, off, 64);
  }
  if (lane == 0) {
    *(float2*)&h2[n * 2] = make_float2(p0, p1);
    as2[n] = p0 * att_src2[0] + p1 * att_src2[1];
    ad2[n] = p0 * att_dst2[0] + p1 * att_dst2[1];
  }
}

// ---------------------------------------------------------------------------
// K5: layer-2 softmax-aggregate (2 ch, single pass) + bias + log_softmax.
// 8 lanes per node.
// ---------------------------------------------------------------------------
__global__ __launch_bounds__(256) void agg2_k(
    const int* __restrict__ offs, const int* __restrict__ csr,
    const float* __restrict__ h2, const float* __restrict__ as2,
    const float* __restrict__ ad2, const float* __restrict__ b2,
    float* __restrict__ out) {
  int t = blockIdx.x * 256 + threadIdx.x;
  int n = t >> 3;
  int sub = t & 7;
  if (n >= NN) return;
  const float adv = ad2[n];
  const int beg = offs[n], end = offs[n + 1];
  const float2* __restrict__ h2v = (const float2*)h2;

  float den = 0.f, a0 = 0.f, a1 = 0.f;
  for (int j = beg + sub; j < end; j += 8) {
    int s = csr[j];
    float e = as2[s] + adv;
    e = (e > 0.f) ? e : NEG_SLOPE * e;
    float ex = __expf(e);
    float2 hv = h2v[s];
    den += ex;
    a0 = fmaf(ex, hv.x, a0);
    a1 = fmaf(ex, hv.y, a1);
  }
  #pragma unroll
  for (int off = 4; off; off >>= 1) {
    den += __shfl_down(den, off, 8);
    a0  += __shfl_down(a0, off, 8);
    a1  += __shfl_down(a1, off, 8);
  }
  if (sub == 0) {
    float inv = 1.f / (den + EPSF);
    float o0 = a0 * inv + b2[0];
    float o1 = a1 * inv + b2[1];
    float mx = fmaxf(o0, o1);
    float lse = mx + __logf(__expf(o0 - mx) + __expf(o1 - mx));
    *(float2*)&out[n * 2] = make_float2(o0 - lse, o1 - lse);
  }
}

// ---------------------------------------------------------------------------
extern "C" void kernel_launch(void* const* d_in, const int* in_sizes, int n_in,
                              void* d_out, int out_size, void* d_ws, size_t ws_size,
                              hipStream_t stream) {
  const float* x        = (const float*)d_in[0];
  const int*   ei       = (const int*)d_in[1];
  const float* W1       = (const float*)d_in[2];
  const float* att_src1 = (const float*)d_in[3];
  const float* att_dst1 = (const float*)d_in[4];
  const float* b1       = (const float*)d_in[5];
  const float* W2       = (const float*)d_in[6];
  const float* att_src2 = (const float*)d_in[7];
  const float* att_dst2 = (const float*)d_in[8];
  const float* b2       = (const float*)d_in[9];
  float* out = (float*)d_out;

  char* p = (char*)d_ws;
  auto alloc = [&](size_t bytes) {
    char* r = p;
    p += (bytes + 255) & ~size_t(255);
    return r;
  };
  uint32* h1b  = (uint32*)alloc(sizeof(uint32) * NN * 64);   // bf16x2 packed
  float* as1   = (float*)alloc(sizeof(float) * NN * 4);
  float* ad1   = (float*)alloc(sizeof(float) * NN * 4);
  float* h2    = (float*)alloc(sizeof(float) * NN * 2);
  float* as2   = (float*)alloc(sizeof(float) * NN);
  float* ad2   = (float*)alloc(sizeof(float) * NN);
  int*   cc    = (int*)alloc(sizeof(int) * NN * 2);          // counts | cursor
  int*   counts = cc;
  int*   cursor = cc + NN;
  int*   offs  = (int*)alloc(sizeof(int) * (NN + 1));
  int*   csr   = (int*)alloc(sizeof(int) * ET);

  hipMemsetAsync(cc, 0, sizeof(int) * NN * 2, stream);

  gemm1_count_k<<<(NN + 31) / 32, 256, 0, stream>>>(x, W1, att_src1, att_dst1, ei,
                                                    h1b, as1, ad1, counts);
  scan_k<<<1, 1024, 0, stream>>>(counts, offs);
  scatter_k<<<(ET + 255) / 256, 256, 0, stream>>>(ei, offs, cursor, csr);
  agg1_k<<<(NN + 3) / 4, 256, 0, stream>>>(offs, csr, h1b, as1, ad1, b1, W2,
                                           att_src2, att_dst2, h2, as2, ad2);
  agg2_k<<<(NN * 8 + 255) / 256, 256, 0, stream>>>(offs, csr, h2, as2, ad2, b2, out);
}

// Round 3
// 236.342 us; speedup vs baseline: 1.9109x; 1.3511x over previous
//
#include <hip/hip_runtime.h>
#include <hip/hip_bf16.h>

#define NN 50000
#define EE 800000
#define ET (EE + NN)   // edges + self-loops
#define NEG_SLOPE 0.2f
#define EPSF 1e-16f

typedef unsigned int uint32;

__device__ __forceinline__ unsigned short f2bf(float f) {
  unsigned int u = __float_as_uint(f);
  unsigned int r = (u + 0x7fffu + ((u >> 16) & 1u)) >> 16;   // RNE
  return (unsigned short)r;
}
__device__ __forceinline__ float bf_lo(uint32 v) { return __uint_as_float(v << 16); }
__device__ __forceinline__ float bf_hi(uint32 v) { return __uint_as_float(v & 0xffff0000u); }

// ---------------------------------------------------------------------------
// K0: h1 = x @ W1 (50000x128 @ 128x128), fused a_src1/a_dst1 epilogue,
// h1 stored as packed bf16x2 (uint per 2 channels). Tail: fused degree count.
// Block = 256 threads -> 32 nodes x 128 ch; thread = 4 nodes x 4 ch.
// ---------------------------------------------------------------------------
__global__ __launch_bounds__(256) void gemm1_count_k(
    const float* __restrict__ x, const float* __restrict__ W1,
    const float* __restrict__ att_src1, const float* __restrict__ att_dst1,
    const int* __restrict__ ei,
    uint32* __restrict__ h1b, float* __restrict__ as1, float* __restrict__ ad1,
    int* __restrict__ counts) {
  __shared__ float Wt[32][128];   // k-tile x channels (16 KB)
  __shared__ float Xt[32][40];    // nodes x k-tile, +8 pad keeps 16B alignment

  const int t  = threadIdx.x;
  const int tx = t & 31;          // channels tx*4 .. tx*4+3
  const int ty = t >> 5;          // node subgroup 0..7 (4 nodes each)
  const int nodeBase = blockIdx.x * 32;

  float acc[4][4];
  #pragma unroll
  for (int i = 0; i < 4; i++)
    #pragma unroll
    for (int j = 0; j < 4; j++) acc[i][j] = 0.f;

  for (int kb = 0; kb < 128; kb += 32) {
    #pragma unroll
    for (int i = 0; i < 4; i++) {
      int v = t + i * 256;             // [0,1024) float4 slots of 32x128 tile
      int row = v >> 5, c4 = v & 31;
      *(float4*)&Wt[row][c4 * 4] =
          *(const float4*)&W1[(kb + row) * 128 + c4 * 4];
    }
    {
      int n = t >> 3, c4 = t & 7;
      int gn = nodeBase + n; if (gn >= NN) gn = NN - 1;
      *(float4*)&Xt[n][c4 * 4] =
          *(const float4*)&x[gn * 128 + kb + c4 * 4];
    }
    __syncthreads();
    #pragma unroll
    for (int k = 0; k < 32; k += 4) {
      float4 xk[4];
      #pragma unroll
      for (int i = 0; i < 4; i++) xk[i] = *(const float4*)&Xt[ty * 4 + i][k];
      #pragma unroll
      for (int kk = 0; kk < 4; kk++) {
        float4 w = *(const float4*)&Wt[k + kk][tx * 4];
        #pragma unroll
        for (int i = 0; i < 4; i++) {
          float xv = (kk == 0) ? xk[i].x : (kk == 1) ? xk[i].y : (kk == 2) ? xk[i].z : xk[i].w;
          acc[i][0] = fmaf(xv, w.x, acc[i][0]);
          acc[i][1] = fmaf(xv, w.y, acc[i][1]);
          acc[i][2] = fmaf(xv, w.z, acc[i][2]);
          acc[i][3] = fmaf(xv, w.w, acc[i][3]);
        }
      }
    }
    __syncthreads();
  }

  const float4 as4 = *(const float4*)&att_src1[tx * 4];  // [4][32] flat == [128]
  const float4 ad4 = *(const float4*)&att_dst1[tx * 4];
  const int head = tx >> 3;

  #pragma unroll
  for (int i = 0; i < 4; i++) {
    int gn = nodeBase + ty * 4 + i;
    float ps = acc[i][0]*as4.x + acc[i][1]*as4.y + acc[i][2]*as4.z + acc[i][3]*as4.w;
    float pd = acc[i][0]*ad4.x + acc[i][1]*ad4.y + acc[i][2]*ad4.z + acc[i][3]*ad4.w;
    #pragma unroll
    for (int off = 4; off; off >>= 1) {
      ps += __shfl_down(ps, off, 8);
      pd += __shfl_down(pd, off, 8);
    }
    if (gn < NN) {
      uint32 p0 = (uint32)f2bf(acc[i][0]) | ((uint32)f2bf(acc[i][1]) << 16);
      uint32 p1 = (uint32)f2bf(acc[i][2]) | ((uint32)f2bf(acc[i][3]) << 16);
      uint2 pk = make_uint2(p0, p1);
      *(uint2*)&h1b[gn * 64 + tx * 2] = pk;
      if ((tx & 7) == 0) {
        as1[gn * 4 + head] = ps;
        ad1[gn * 4 + head] = pd;
      }
    }
  }

  // fused degree count (counts pre-zeroed by memset on the same stream)
  const int stride = gridDim.x * 256;
  for (int i = blockIdx.x * 256 + t; i < ET; i += stride) {
    int d = (i < EE) ? ei[EE + i] : (i - EE);
    atomicAdd(&counts[d], 1);
  }
}

// ---------------------------------------------------------------------------
// offs_k: allocate each node's contiguous CSR segment. Order within csr is
// arbitrary (softmax aggregation is order-invariant), so no global scan is
// needed: wave-level exclusive prefix + one atomicAdd per wave on a cursor.
// ---------------------------------------------------------------------------
__global__ __launch_bounds__(256) void offs_k(const int* __restrict__ counts,
                                              int* __restrict__ offs,
                                              int* __restrict__ gcur) {
  const int n = blockIdx.x * 256 + threadIdx.x;
  const int lane = threadIdx.x & 63;
  int cnt = (n < NN) ? counts[n] : 0;
  int inc = cnt;
  #pragma unroll
  for (int off = 1; off < 64; off <<= 1) {
    int v = __shfl_up(inc, off, 64);
    if (lane >= off) inc += v;
  }
  int total = __shfl(inc, 63, 64);
  int base = 0;
  if (lane == 63) base = atomicAdd(gcur, total);
  base = __shfl(base, 63, 64);
  if (n < NN) offs[n] = base + inc - cnt;
}

__global__ void scatter_k(const int* __restrict__ ei, const int* __restrict__ offs,
                          int* __restrict__ cursor, int* __restrict__ csr) {
  int i = blockIdx.x * blockDim.x + threadIdx.x;
  if (i >= ET) return;
  int s, d;
  if (i < EE) { s = ei[i]; d = ei[EE + i]; }
  else        { s = d = i - EE; }
  int pos = offs[d] + atomicAdd(&cursor[d], 1);
  csr[pos] = s;
}

// ---------------------------------------------------------------------------
// K4: layer-1 softmax-aggregate (single pass, no max-shift) + bias + ELU +
// (out1 @ W2) + att2 dots. One wave per node; lane = channels 2l, 2l+1.
// ---------------------------------------------------------------------------
__global__ __launch_bounds__(256) void agg1_k(
    const int* __restrict__ offs, const int* __restrict__ counts,
    const int* __restrict__ csr,
    const uint32* __restrict__ h1b, const float* __restrict__ as1,
    const float* __restrict__ ad1, const float* __restrict__ b1,
    const float* __restrict__ W2, const float* __restrict__ att_src2,
    const float* __restrict__ att_dst2,
    float* __restrict__ h2, float* __restrict__ as2, float* __restrict__ ad2) {
  const int lane = threadIdx.x & 63;
  const int n = __builtin_amdgcn_readfirstlane(blockIdx.x * 4 + (threadIdx.x >> 6));
  const int hd = lane >> 4;

  const int beg = __builtin_amdgcn_readfirstlane(offs[n]);
  const int end = beg + __builtin_amdgcn_readfirstlane(counts[n]);
  const float adv = ad1[n * 4 + hd];

  float den = 0.f, accx = 0.f, accy = 0.f;
  int j = beg;
  for (; j + 3 < end; j += 4) {
    int s0 = csr[j], s1 = csr[j + 1], s2 = csr[j + 2], s3 = csr[j + 3];
    float e0 = as1[s0 * 4 + hd] + adv;
    float e1 = as1[s1 * 4 + hd] + adv;
    float e2 = as1[s2 * 4 + hd] + adv;
    float e3 = as1[s3 * 4 + hd] + adv;
    uint32 v0 = h1b[s0 * 64 + lane];
    uint32 v1 = h1b[s1 * 64 + lane];
    uint32 v2 = h1b[s2 * 64 + lane];
    uint32 v3 = h1b[s3 * 64 + lane];
    e0 = (e0 > 0.f) ? e0 : NEG_SLOPE * e0;
    e1 = (e1 > 0.f) ? e1 : NEG_SLOPE * e1;
    e2 = (e2 > 0.f) ? e2 : NEG_SLOPE * e2;
    e3 = (e3 > 0.f) ? e3 : NEG_SLOPE * e3;
    float x0 = __expf(e0), x1 = __expf(e1), x2 = __expf(e2), x3 = __expf(e3);
    den += (x0 + x1) + (x2 + x3);
    accx = fmaf(x0, bf_lo(v0), accx);
    accy = fmaf(x0, bf_hi(v0), accy);
    accx = fmaf(x1, bf_lo(v1), accx);
    accy = fmaf(x1, bf_hi(v1), accy);
    accx = fmaf(x2, bf_lo(v2), accx);
    accy = fmaf(x2, bf_hi(v2), accy);
    accx = fmaf(x3, bf_lo(v3), accx);
    accy = fmaf(x3, bf_hi(v3), accy);
  }
  for (; j < end; j++) {
    int s = csr[j];
    float e = as1[s * 4 + hd] + adv;
    e = (e > 0.f) ? e : NEG_SLOPE * e;
    float ex = __expf(e);
    uint32 v = h1b[s * 64 + lane];
    den += ex;
    accx = fmaf(ex, bf_lo(v), accx);
    accy = fmaf(ex, bf_hi(v), accy);
  }

  float inv = 1.f / (den + EPSF);
  float2 bb = ((const float2*)b1)[lane];
  float ox = accx * inv + bb.x;
  float oy = accy * inv + bb.y;
  ox = (ox > 0.f) ? ox : (__expf(ox) - 1.f);   // ELU
  oy = (oy > 0.f) ? oy : (__expf(oy) - 1.f);

  float4 wq = ((const float4*)W2)[lane];  // rows 2l, 2l+1 of W2[128][2]
  float p0 = ox * wq.x + oy * wq.z;
  float p1 = ox * wq.y + oy * wq.w;
  #pragma unroll
  for (int off = 32; off; off >>= 1) {
    p0 += __shfl_xor(p0, off, 64);
    p1 += __shfl_xor(p1, off, 64);
  }
  if (lane == 0) {
    *(float2*)&h2[n * 2] = make_float2(p0, p1);
    as2[n] = p0 * att_src2[0] + p1 * att_src2[1];
    ad2[n] = p0 * att_dst2[0] + p1 * att_dst2[1];
  }
}

// ---------------------------------------------------------------------------
// K5: layer-2 softmax-aggregate (2 ch, single pass) + bias + log_softmax.
// 8 lanes per node.
// ---------------------------------------------------------------------------
__global__ __launch_bounds__(256) void agg2_k(
    const int* __restrict__ offs, const int* __restrict__ counts,
    const int* __restrict__ csr,
    const float* __restrict__ h2, const float* __restrict__ as2,
    const float* __restrict__ ad2, const float* __restrict__ b2,
    float* __restrict__ out) {
  int t = blockIdx.x * 256 + threadIdx.x;
  int n = t >> 3;
  int sub = t & 7;
  if (n >= NN) return;
  const float adv = ad2[n];
  const int beg = offs[n], end = beg + counts[n];
  const float2* __restrict__ h2v = (const float2*)h2;

  float den = 0.f, a0 = 0.f, a1 = 0.f;
  for (int j = beg + sub; j < end; j += 8) {
    int s = csr[j];
    float e = as2[s] + adv;
    e = (e > 0.f) ? e : NEG_SLOPE * e;
    float ex = __expf(e);
    float2 hv = h2v[s];
    den += ex;
    a0 = fmaf(ex, hv.x, a0);
    a1 = fmaf(ex, hv.y, a1);
  }
  #pragma unroll
  for (int off = 4; off; off >>= 1) {
    den += __shfl_down(den, off, 8);
    a0  += __shfl_down(a0, off, 8);
    a1  += __shfl_down(a1, off, 8);
  }
  if (sub == 0) {
    float inv = 1.f / (den + EPSF);
    float o0 = a0 * inv + b2[0];
    float o1 = a1 * inv + b2[1];
    float mx = fmaxf(o0, o1);
    float lse = mx + __logf(__expf(o0 - mx) + __expf(o1 - mx));
    *(float2*)&out[n * 2] = make_float2(o0 - lse, o1 - lse);
  }
}

// ---------------------------------------------------------------------------
extern "C" void kernel_launch(void* const* d_in, const int* in_sizes, int n_in,
                              void* d_out, int out_size, void* d_ws, size_t ws_size,
                              hipStream_t stream) {
  const float* x        = (const float*)d_in[0];
  const int*   ei       = (const int*)d_in[1];
  const float* W1       = (const float*)d_in[2];
  const float* att_src1 = (const float*)d_in[3];
  const float* att_dst1 = (const float*)d_in[4];
  const float* b1       = (const float*)d_in[5];
  const float* W2       = (const float*)d_in[6];
  const float* att_src2 = (const float*)d_in[7];
  const float* att_dst2 = (const float*)d_in[8];
  const float* b2       = (const float*)d_in[9];
  float* out = (float*)d_out;

  char* p = (char*)d_ws;
  auto alloc = [&](size_t bytes) {
    char* r = p;
    p += (bytes + 255) & ~size_t(255);
    return r;
  };
  uint32* h1b  = (uint32*)alloc(sizeof(uint32) * NN * 64);   // bf16x2 packed
  float* as1   = (float*)alloc(sizeof(float) * NN * 4);
  float* ad1   = (float*)alloc(sizeof(float) * NN * 4);
  float* h2    = (float*)alloc(sizeof(float) * NN * 2);
  float* as2   = (float*)alloc(sizeof(float) * NN);
  float* ad2   = (float*)alloc(sizeof(float) * NN);
  int*   cc    = (int*)alloc(sizeof(int) * (NN * 2 + 64)); // counts | cursor | gcur
  int*   counts = cc;
  int*   cursor = cc + NN;
  int*   gcur   = cc + NN * 2;
  int*   offs  = (int*)alloc(sizeof(int) * (NN + 1));
  int*   csr   = (int*)alloc(sizeof(int) * ET);

  hipMemsetAsync(cc, 0, sizeof(int) * (NN * 2 + 64), stream);

  gemm1_count_k<<<(NN + 31) / 32, 256, 0, stream>>>(x, W1, att_src1, att_dst1, ei,
                                                    h1b, as1, ad1, counts);
  offs_k<<<(NN + 255) / 256, 256, 0, stream>>>(counts, offs, gcur);
  scatter_k<<<(ET + 255) / 256, 256, 0, stream>>>(ei, offs, cursor, csr);
  agg1_k<<<(NN + 3) / 4, 256, 0, stream>>>(offs, counts, csr, h1b, as1, ad1, b1, W2,
                                           att_src2, att_dst2, h2, as2, ad2);
  agg2_k<<<(NN * 8 + 255) / 256, 256, 0, stream>>>(offs, counts, csr, h2, as2, ad2, b2, out);
}